// Round 3
// baseline (390.380 us; speedup 1.0000x reference)
//
#include <hip/hip_runtime.h>
#include <hip/hip_bf16.h>
#include <cstdint>
#include <cstddef>

typedef __bf16 bf16_t;
typedef bf16_t bf16x8 __attribute__((ext_vector_type(8)));
typedef bf16_t bf16x4v __attribute__((ext_vector_type(4)));
typedef float floatx4 __attribute__((ext_vector_type(4)));

static constexpr int B_ = 8192;   // batch
static constexpr int H_ = 1024;   // hidden
static constexpr int G4 = 4096;   // 4*H
static constexpr int K_ = 1024;   // input size == hidden size

// ---- async global->LDS, 16B per lane (lane's dest = uniform base + lane*16)
__device__ inline void async_copy16(const bf16_t* g, bf16_t* l) {
  auto l3 = (__attribute__((address_space(3))) void*)(uint32_t)(uintptr_t)l;
  __builtin_amdgcn_global_load_lds(
      (__attribute__((address_space(1))) void*)(uintptr_t)g, l3, 16, 0, 0);
}

// ---------------- fused prep: casts + weight permute, ONE launch ------------
// blocks [0,8192):    input+hx fp32 -> bf16, 8 elems/thread
// blocks [8192,24576): weight rows fp32 -> bf16 with gate-interleave perm
//                      (out row r' = h*4+g  <-  in row r = g*1024+h)
__global__ __launch_bounds__(256) void prep_all(
    const float* __restrict__ input, const float* __restrict__ hx,
    const float* __restrict__ wih, const float* __restrict__ whh,
    bf16_t* __restrict__ Abf, bf16_t* __restrict__ Hbf,
    bf16_t* __restrict__ Wib, bf16_t* __restrict__ Whb) {
  const int bid = blockIdx.x;
  if (bid < 8192) {
    const int n8 = B_ * K_ / 8;                 // 1M per tensor
    int gid = bid * 256 + threadIdx.x;          // [0, 2M)
    const float* src; bf16_t* dst; int idx;
    if (gid < n8) { src = input; dst = Abf; idx = gid; }
    else          { src = hx;    dst = Hbf; idx = gid - n8; }
    const float4 v0 = ((const float4*)src)[idx * 2];
    const float4 v1 = ((const float4*)src)[idx * 2 + 1];
    bf16x8 o;
    o[0] = (bf16_t)v0.x; o[1] = (bf16_t)v0.y; o[2] = (bf16_t)v0.z; o[3] = (bf16_t)v0.w;
    o[4] = (bf16_t)v1.x; o[5] = (bf16_t)v1.y; o[6] = (bf16_t)v1.z; o[7] = (bf16_t)v1.w;
    ((bf16x8*)dst)[idx] = o;
  } else {
    const int r = bid - 8192;                   // [0, 16384)
    const int rp = r & 4095;                    // output row within matrix
    const float* src = (r < 4096) ? wih : whh;
    bf16_t*      dst = (r < 4096) ? Wib : Whb;
    const int h = rp >> 2, g = rp & 3;
    const int rin = g * 1024 + h;
    const int c = threadIdx.x * 4;
    const float4 v = *(const float4*)(src + (size_t)rin * K_ + c);
    bf16x4v o;
    o[0] = (bf16_t)v.x; o[1] = (bf16_t)v.y; o[2] = (bf16_t)v.z; o[3] = (bf16_t)v.w;
    *(bf16x4v*)(dst + (size_t)rp * K_ + c) = o;
  }
}

// ---------------- dual GEMM: C = A * W^T (both K-major), bf16 in/out --------
// 256x256 8-phase template (m201 structure): BK=64, 8 waves (2Mx4N), 512 thr,
// 128 KiB LDS double-buffer, raw s_barrier (loads survive barriers),
// counted vmcnt(4) once per K-tile (never 0 in the loop), setprio(1) around
// each 16-MFMA cluster. LDS swizzle: 16B chunk slot = chunk ^ (row&7),
// realized as inverse-swizzled GLOBAL source + linear global_load_lds dest
// (rule #21) + swizzled ds_read addresses -> fragment reads are 2-way (free).
// XCD swizzle (bijective, 1024 blocks % 8 == 0): each XCD owns whole M-tile
// rows so A-panels stay XCD-L2-resident.
//
// Stage schedule (race-free vs double buffer), iteration t (buffer p=t&1,q=p^1):
//   ph1: read A(p,qm0)+B(p,qn0); issue (t+1).A0 -> q     | MFMA quad(0,0)
//   ph2: read B(p,qn1);          issue (t+1).A1 -> q     | MFMA quad(0,1)
//   ph3: read A(p,qm1);          issue (t+2).B0 -> p (*) | MFMA quad(1,0)
//   ph4:                          issue (t+2).B1 -> p (*) | MFMA quad(1,1); vmcnt(4)
// (*) legal: all B-reads of buffer p completed by ph2's closing barrier.

#define FENCE() asm volatile("" ::: "memory")
#define BARRIER() do { FENCE(); __builtin_amdgcn_s_barrier(); FENCE(); } while (0)

__global__ __launch_bounds__(512, 2) void gemm_bt_dual8(
    const bf16_t* __restrict__ A0, const bf16_t* __restrict__ A1,
    const bf16_t* __restrict__ W0, const bf16_t* __restrict__ W1,
    bf16_t* __restrict__ C0, bf16_t* __restrict__ C1) {
  constexpr int N = G4, K = K_, NT = K_ / 64;

  __shared__ bf16_t ldsA[2][16384];   // [buf][256 rows x 64 cols]
  __shared__ bf16_t ldsB[2][16384];

  // bijective XCD swizzle of flat block id (x fastest in dispatch order)
  const int flatb = blockIdx.x + (blockIdx.y << 4) + (blockIdx.z << 9);
  const int swzb  = (flatb & 7) * 128 + (flatb >> 3);
  const int bz = swzb >> 9;
  const int by = (swzb >> 4) & 31;
  const int bx = swzb & 15;

  const bf16_t* A = bz ? A1 : A0;
  const bf16_t* W = bz ? W1 : W0;
  bf16_t*       C = bz ? C1 : C0;

  const int tid  = threadIdx.x;
  const int lane = tid & 63;
  const int w    = tid >> 6;          // wave 0..7
  const int wm   = w >> 2, wn = w & 3;
  const int lrow = lane & 15, quad = lane >> 4;
  const int e    = lrow & 7;

  const int m0 = by * 256;
  const int n0 = bx * 256;

  // staging: thread t covers LDS 16B slot t of an 8KB sub-half (64 rows x 64
  // cols). row = t>>3, slot = t&7; global source chunk = slot ^ (row&7).
  const int srow   = tid >> 3;
  const int schunk = (tid & 7) ^ (srow & 7);
  const bf16_t* gA = A + (size_t)(m0 + srow) * K + schunk * 8;
  const bf16_t* gB = W + (size_t)(n0 + srow) * K + schunk * 8;
  const int wslot = w * 512;          // wave-uniform elem offset in sub-half

  // fragment read bases (elements), swizzled chunk = (ks*4+quad) ^ e
  const int aBase = (wm * 128 + lrow) * 64 + (quad ^ e) * 8;
  const int bBase = (wn * 64 + lrow) * 64 + (quad ^ e) * 8;

  floatx4 acc[8][4] = {};
  bf16x8 aF[4][2];       // current qm: 4 row-blocks x 2 k-halves
  bf16x8 bF[2][2][2];    // [qn][j2][ks], both qn kept for the whole K-tile

#define STG_A(p, half, kt) do {                                          \
    bf16_t* _l = &ldsA[p][(half) * 8192 + wslot];                        \
    async_copy16(gA + (size_t)((half) * 128) * K + (kt) * 64, _l);       \
    async_copy16(gA + (size_t)((half) * 128 + 64) * K + (kt) * 64, _l + 4096); \
  } while (0)
#define STG_B(p, half, kt) do {                                          \
    bf16_t* _l = &ldsB[p][(half) * 8192 + wslot];                        \
    async_copy16(gB + (size_t)((half) * 128) * K + (kt) * 64, _l);       \
    async_copy16(gB + (size_t)((half) * 128 + 64) * K + (kt) * 64, _l + 4096); \
  } while (0)

#define LD_A(p, qm) do { _Pragma("unroll")                               \
    for (int i2 = 0; i2 < 4; ++i2) {                                     \
      const int o = aBase + (qm) * 4096 + i2 * 1024;                     \
      aF[i2][0] = *(const bf16x8*)&ldsA[p][o];                           \
      aF[i2][1] = *(const bf16x8*)&ldsA[p][o ^ 32];                      \
    } } while (0)
#define LD_B(p, qn) do { _Pragma("unroll")                               \
    for (int j2 = 0; j2 < 2; ++j2) {                                     \
      const int o = bBase + (qn) * 2048 + j2 * 1024;                     \
      bF[qn][j2][0] = *(const bf16x8*)&ldsB[p][o];                       \
      bF[qn][j2][1] = *(const bf16x8*)&ldsB[p][o ^ 32];                  \
    } } while (0)
#define MFMA_Q(qm, qn) do { _Pragma("unroll")                            \
    for (int i2 = 0; i2 < 4; ++i2) { _Pragma("unroll")                   \
      for (int j2 = 0; j2 < 2; ++j2) {                                   \
        floatx4& c = acc[(qm) * 4 + i2][(qn) * 2 + j2];                  \
        c = __builtin_amdgcn_mfma_f32_16x16x32_bf16(aF[i2][0], bF[qn][j2][0], c, 0, 0, 0); \
        c = __builtin_amdgcn_mfma_f32_16x16x32_bf16(aF[i2][1], bF[qn][j2][1], c, 0, 0, 0); \
      } } } while (0)

  // prologue: tile0 complete + tile1 B-halves; wait tile0 (leave tile1.B in flight)
  STG_B(0, 0, 0); STG_B(0, 1, 0);
  STG_A(0, 0, 0); STG_A(0, 1, 0);
  STG_B(1, 0, 1); STG_B(1, 1, 1);
  asm volatile("s_waitcnt vmcnt(4)" ::: "memory");
  BARRIER();

#pragma unroll 2
  for (int t = 0; t < NT; ++t) {
    const int p = t & 1, q = p ^ 1;
    const int t1 = (t + 1) & (NT - 1), t2 = (t + 2) & (NT - 1);

    // ---- phase 1: quadrant (0,0)
    LD_A(p, 0); LD_B(p, 0);
    STG_A(q, 0, t1);
    BARRIER();
    asm volatile("s_waitcnt lgkmcnt(0)" ::: "memory");
    __builtin_amdgcn_sched_barrier(0);
    __builtin_amdgcn_s_setprio(1); MFMA_Q(0, 0); __builtin_amdgcn_s_setprio(0);
    BARRIER();

    // ---- phase 2: quadrant (0,1)
    LD_B(p, 1);
    STG_A(q, 1, t1);
    BARRIER();
    asm volatile("s_waitcnt lgkmcnt(0)" ::: "memory");
    __builtin_amdgcn_sched_barrier(0);
    __builtin_amdgcn_s_setprio(1); MFMA_Q(0, 1); __builtin_amdgcn_s_setprio(0);
    BARRIER();

    // ---- phase 3: quadrant (1,0)
    LD_A(p, 1);
    STG_B(p, 0, t2);
    BARRIER();
    asm volatile("s_waitcnt lgkmcnt(0)" ::: "memory");
    __builtin_amdgcn_sched_barrier(0);
    __builtin_amdgcn_s_setprio(1); MFMA_Q(1, 0); __builtin_amdgcn_s_setprio(0);
    BARRIER();

    // ---- phase 4: quadrant (1,1); counted vmcnt AFTER the MFMA cluster
    STG_B(p, 1, t2);
    BARRIER();
    __builtin_amdgcn_s_setprio(1); MFMA_Q(1, 1); __builtin_amdgcn_s_setprio(0);
    asm volatile("s_waitcnt vmcnt(4)" ::: "memory");
    BARRIER();
  }

  // C/D layout (m89-verified): col(n)=lane&15, row(m)=quad*4+reg
#pragma unroll
  for (int i = 0; i < 8; ++i) {
    const int mbase = m0 + wm * 128 + i * 16 + quad * 4;
#pragma unroll
    for (int j = 0; j < 4; ++j) {
      const int n = n0 + wn * 64 + j * 16 + lrow;
#pragma unroll
      for (int r = 0; r < 4; ++r)
        C[(size_t)(mbase + r) * N + n] = (bf16_t)acc[i][j][r];
    }
  }
#undef STG_A
#undef STG_B
#undef LD_A
#undef LD_B
#undef MFMA_Q
}

// ---------------- fused epilogue: WAVE-PER-ROW, no __syncthreads ------------
// 4 waves/block, one batch row per wave. Lane l owns h in {e*64+l, e=0..15}.
// Gate loads: gate-interleaved IG/HG -> bf16x4 (8B/lane, 512B/wave contig).
// Both LN reductions are 64-lane __shfl_xor butterflies (no LDS, no barrier).
__device__ inline float sigmoid_f(float x) { return 1.0f / (1.0f + __expf(-x)); }
__device__ inline float tanh_f(float x) {
  float e = __expf(2.0f * x);
  return 1.0f - 2.0f / (e + 1.0f);   // safe at +/-inf
}

__global__ __launch_bounds__(256) void ln_lstm_epi_wave(
    const bf16_t* __restrict__ IG, const bf16_t* __restrict__ HG,
    const float* __restrict__ cx,
    const float* __restrict__ wi, const float* __restrict__ bi,
    const float* __restrict__ wh, const float* __restrict__ bh,
    const float* __restrict__ wc, const float* __restrict__ bc,
    float* __restrict__ hy_out, float* __restrict__ cy_out) {
  const int l = threadIdx.x & 63;
  const int b = blockIdx.x * 4 + (threadIdx.x >> 6);

  const bf16_t* igp = IG + (size_t)b * 4096;
  const bf16_t* hgp = HG + (size_t)b * 4096;

  bf16x4v ig[16], hg[16];
  float cxv[16];
#pragma unroll
  for (int e = 0; e < 16; ++e) {
    const int h = e * 64 + l;
    ig[e] = *(const bf16x4v*)(igp + h * 4);
    hg[e] = *(const bf16x4v*)(hgp + h * 4);
    cxv[e] = cx[(size_t)b * 1024 + h];
  }

  float si = 0, qi = 0, sh = 0, qh = 0;
#pragma unroll
  for (int e = 0; e < 16; ++e)
#pragma unroll
    for (int g = 0; g < 4; ++g) {
      const float a = (float)ig[e][g], c = (float)hg[e][g];
      si += a; qi = fmaf(a, a, qi);
      sh += c; qh = fmaf(c, c, qh);
    }
#pragma unroll
  for (int off = 1; off < 64; off <<= 1) {
    si += __shfl_xor(si, off); qi += __shfl_xor(qi, off);
    sh += __shfl_xor(sh, off); qh += __shfl_xor(qh, off);
  }
  const float invN = 1.0f / 4096.0f;
  const float mui = si * invN, muh = sh * invN;
  const float rsi = rsqrtf(fmaxf(qi * invN - mui * mui, 0.0f) + 1e-5f);
  const float rsh = rsqrtf(fmaxf(qh * invN - muh * muh, 0.0f) + 1e-5f);

  float cv[16], ov[16];
  float sc = 0, qc = 0;
#pragma unroll
  for (int e = 0; e < 16; ++e) {
    const int h = e * 64 + l;
    float G[4];
#pragma unroll
    for (int g = 0; g < 4; ++g)
      G[g] = ((float)ig[e][g] - mui) * rsi * wi[g * 1024 + h] + bi[g * 1024 + h] +
             ((float)hg[e][g] - muh) * rsh * wh[g * 1024 + h] + bh[g * 1024 + h];
    const float in_g = sigmoid_f(G[0]);
    const float fo_g = sigmoid_f(G[1]);
    const float ce_g = tanh_f(G[2]);
    ov[e] = sigmoid_f(G[3]);
    const float c = fo_g * cxv[e] + in_g * ce_g;
    cv[e] = c;
    sc += c; qc = fmaf(c, c, qc);
  }
#pragma unroll
  for (int off = 1; off < 64; off <<= 1) {
    sc += __shfl_xor(sc, off); qc += __shfl_xor(qc, off);
  }
  const float invH = 1.0f / 1024.0f;
  const float muc = sc * invH;
  const float rsc = rsqrtf(fmaxf(qc * invH - muc * muc, 0.0f) + 1e-5f);

#pragma unroll
  for (int e = 0; e < 16; ++e) {
    const int h = e * 64 + l;
    const float cyn = (cv[e] - muc) * rsc * wc[h] + bc[h];
    cy_out[(size_t)b * 1024 + h] = cyn;
    hy_out[(size_t)b * 1024 + h] = ov[e] * tanh_f(cyn);
  }
}

extern "C" void kernel_launch(void* const* d_in, const int* in_sizes, int n_in,
                              void* d_out, int out_size, void* d_ws, size_t ws_size,
                              hipStream_t stream) {
  const float* input  = (const float*)d_in[0];
  const float* hx     = (const float*)d_in[1];
  const float* cx     = (const float*)d_in[2];
  const float* w_ih   = (const float*)d_in[3];
  const float* w_hh   = (const float*)d_in[4];
  const float* ln_i_w = (const float*)d_in[5];
  const float* ln_i_b = (const float*)d_in[6];
  const float* ln_h_w = (const float*)d_in[7];
  const float* ln_h_b = (const float*)d_in[8];
  const float* ln_c_w = (const float*)d_in[9];
  const float* ln_c_b = (const float*)d_in[10];

  float* out = (float*)d_out;
  float* hy = out;
  float* cy = out + (size_t)B_ * H_;

  // workspace (bf16): A 16MB | H 16MB | Wih 8MB | Whh 8MB | IG 64MB | HG 64MB
  bf16_t* Abf = (bf16_t*)d_ws;
  bf16_t* Hbf = Abf + (size_t)B_ * K_;
  bf16_t* Wib = Hbf + (size_t)B_ * K_;
  bf16_t* Whb = Wib + (size_t)G4 * K_;
  bf16_t* IG  = Whb + (size_t)G4 * K_;
  bf16_t* HG  = IG + (size_t)B_ * G4;

  prep_all<<<24576, 256, 0, stream>>>(input, hx, w_ih, w_hh, Abf, Hbf, Wib, Whb);

  gemm_bt_dual8<<<dim3(G4 / 256, B_ / 256, 2), 512, 0, stream>>>(Abf, Hbf, Wib, Whb, IG, HG);

  ln_lstm_epi_wave<<<B_ / 4, 256, 0, stream>>>(IG, HG, cx, ln_i_w, ln_i_b,
                                               ln_h_w, ln_h_b, ln_c_w, ln_c_b, hy, cy);
}

// Round 4
// 362.684 us; speedup vs baseline: 1.0764x; 1.0764x over previous
//
#include <hip/hip_runtime.h>
#include <hip/hip_bf16.h>
#include <cstdint>
#include <cstddef>

typedef __bf16 bf16_t;
typedef bf16_t bf16x8 __attribute__((ext_vector_type(8)));
typedef bf16_t bf16x4v __attribute__((ext_vector_type(4)));
typedef float floatx4 __attribute__((ext_vector_type(4)));

static constexpr int B_ = 8192;   // batch
static constexpr int H_ = 1024;   // hidden
static constexpr int G4 = 4096;   // 4*H
static constexpr int K_ = 1024;   // input size == hidden size

// ---- async global->LDS, 16B per lane (lane's dest = uniform base + lane*16)
__device__ inline void async_copy16(const bf16_t* g, bf16_t* l) {
  auto l3 = (__attribute__((address_space(3))) void*)(uint32_t)(uintptr_t)l;
  __builtin_amdgcn_global_load_lds(
      (__attribute__((address_space(1))) void*)(uintptr_t)g, l3, 16, 0, 0);
}

// ---------------- fused prep: casts + weight permute, ONE launch ------------
// blocks [0,8192):    input+hx fp32 -> bf16, 8 elems/thread
// blocks [8192,24576): weight rows fp32 -> bf16 with gate-interleave perm
//                      (out row r' = h*4+g  <-  in row r = g*1024+h)
__global__ __launch_bounds__(256) void prep_all(
    const float* __restrict__ input, const float* __restrict__ hx,
    const float* __restrict__ wih, const float* __restrict__ whh,
    bf16_t* __restrict__ Abf, bf16_t* __restrict__ Hbf,
    bf16_t* __restrict__ Wib, bf16_t* __restrict__ Whb) {
  const int bid = blockIdx.x;
  if (bid < 8192) {
    const int n8 = B_ * K_ / 8;                 // 1M per tensor
    int gid = bid * 256 + threadIdx.x;          // [0, 2M)
    const float* src; bf16_t* dst; int idx;
    if (gid < n8) { src = input; dst = Abf; idx = gid; }
    else          { src = hx;    dst = Hbf; idx = gid - n8; }
    const float4 v0 = ((const float4*)src)[idx * 2];
    const float4 v1 = ((const float4*)src)[idx * 2 + 1];
    bf16x8 o;
    o[0] = (bf16_t)v0.x; o[1] = (bf16_t)v0.y; o[2] = (bf16_t)v0.z; o[3] = (bf16_t)v0.w;
    o[4] = (bf16_t)v1.x; o[5] = (bf16_t)v1.y; o[6] = (bf16_t)v1.z; o[7] = (bf16_t)v1.w;
    ((bf16x8*)dst)[idx] = o;
  } else {
    const int r = bid - 8192;                   // [0, 16384)
    const int rp = r & 4095;                    // output row within matrix
    const float* src = (r < 4096) ? wih : whh;
    bf16_t*      dst = (r < 4096) ? Wib : Whb;
    const int h = rp >> 2, g = rp & 3;
    const int rin = g * 1024 + h;
    const int c = threadIdx.x * 4;
    const float4 v = *(const float4*)(src + (size_t)rin * K_ + c);
    bf16x4v o;
    o[0] = (bf16_t)v.x; o[1] = (bf16_t)v.y; o[2] = (bf16_t)v.z; o[3] = (bf16_t)v.w;
    *(bf16x4v*)(dst + (size_t)rp * K_ + c) = o;
  }
}

// ---------------- dual GEMM: C = A * W^T (both K-major), bf16 in/out --------
// 256x256 8-phase template (m201 structure): BK=64, 8 waves (2Mx4N), 512 thr,
// 128 KiB LDS double-buffer, raw s_barrier (loads survive barriers),
// counted vmcnt(4) once per K-tile (never 0 in the loop), setprio(1) around
// each 16-MFMA cluster. LDS swizzle: 16B chunk slot = chunk ^ (row&7),
// realized as inverse-swizzled GLOBAL source + linear global_load_lds dest
// (rule #21) + swizzled ds_read addresses -> fragment reads are 2-way (free).
// XCD swizzle (bijective, 1024 blocks % 8 == 0): each XCD owns whole M-tile
// rows so A-panels stay XCD-L2-resident.
//
// Stage schedule (race-free vs double buffer), iteration t (buffer p=t&1,q=p^1):
//   ph1: read A(p,qm0)+B(p,qn0); issue (t+1).A0 -> q     | MFMA quad(0,0)
//   ph2: read B(p,qn1);          issue (t+1).A1 -> q     | MFMA quad(0,1)
//   ph3: read A(p,qm1);          issue (t+2).B0 -> p (*) | MFMA quad(1,0)
//   ph4:                          issue (t+2).B1 -> p (*) | MFMA quad(1,1); vmcnt(4)
// (*) legal: all B-reads of buffer p completed by ph2's closing barrier.

#define FENCE() asm volatile("" ::: "memory")
#define BARRIER() do { FENCE(); __builtin_amdgcn_s_barrier(); FENCE(); } while (0)

__global__ __launch_bounds__(512, 2) void gemm_bt_dual8(
    const bf16_t* __restrict__ A0, const bf16_t* __restrict__ A1,
    const bf16_t* __restrict__ W0, const bf16_t* __restrict__ W1,
    bf16_t* __restrict__ C0, bf16_t* __restrict__ C1) {
  constexpr int N = G4, K = K_, NT = K_ / 64;

  __shared__ bf16_t ldsA[2][16384];   // [buf][256 rows x 64 cols]
  __shared__ bf16_t ldsB[2][16384];

  // bijective XCD swizzle of flat block id (x fastest in dispatch order)
  const int flatb = blockIdx.x + (blockIdx.y << 4) + (blockIdx.z << 9);
  const int swzb  = (flatb & 7) * 128 + (flatb >> 3);
  const int bz = swzb >> 9;
  const int by = (swzb >> 4) & 31;
  const int bx = swzb & 15;

  const bf16_t* A = bz ? A1 : A0;
  const bf16_t* W = bz ? W1 : W0;
  bf16_t*       C = bz ? C1 : C0;

  const int tid  = threadIdx.x;
  const int lane = tid & 63;
  const int w    = tid >> 6;          // wave 0..7
  const int wm   = w >> 2, wn = w & 3;
  const int lrow = lane & 15, quad = lane >> 4;
  const int e    = lrow & 7;

  const int m0 = by * 256;
  const int n0 = bx * 256;

  // staging: thread t covers LDS 16B slot t of an 8KB sub-half (64 rows x 64
  // cols). row = t>>3, slot = t&7; global source chunk = slot ^ (row&7).
  const int srow   = tid >> 3;
  const int schunk = (tid & 7) ^ (srow & 7);
  const bf16_t* gA = A + (size_t)(m0 + srow) * K + schunk * 8;
  const bf16_t* gB = W + (size_t)(n0 + srow) * K + schunk * 8;
  const int wslot = w * 512;          // wave-uniform elem offset in sub-half

  // fragment read bases (elements), swizzled chunk = (ks*4+quad) ^ e
  const int aBase = (wm * 128 + lrow) * 64 + (quad ^ e) * 8;
  const int bBase = (wn * 64 + lrow) * 64 + (quad ^ e) * 8;

  floatx4 acc[8][4] = {};
  bf16x8 aF[4][2];       // current qm: 4 row-blocks x 2 k-halves
  bf16x8 bF[2][2][2];    // [qn][j2][ks], both qn kept for the whole K-tile

#define STG_A(p, half, kt) do {                                          \
    bf16_t* _l = &ldsA[p][(half) * 8192 + wslot];                        \
    async_copy16(gA + (size_t)((half) * 128) * K + (kt) * 64, _l);       \
    async_copy16(gA + (size_t)((half) * 128 + 64) * K + (kt) * 64, _l + 4096); \
  } while (0)
#define STG_B(p, half, kt) do {                                          \
    bf16_t* _l = &ldsB[p][(half) * 8192 + wslot];                        \
    async_copy16(gB + (size_t)((half) * 128) * K + (kt) * 64, _l);       \
    async_copy16(gB + (size_t)((half) * 128 + 64) * K + (kt) * 64, _l + 4096); \
  } while (0)

#define LD_A(p, qm) do { _Pragma("unroll")                               \
    for (int i2 = 0; i2 < 4; ++i2) {                                     \
      const int o = aBase + (qm) * 4096 + i2 * 1024;                     \
      aF[i2][0] = *(const bf16x8*)&ldsA[p][o];                           \
      aF[i2][1] = *(const bf16x8*)&ldsA[p][o ^ 32];                      \
    } } while (0)
#define LD_B(p, qn) do { _Pragma("unroll")                               \
    for (int j2 = 0; j2 < 2; ++j2) {                                     \
      const int o = bBase + (qn) * 2048 + j2 * 1024;                     \
      bF[qn][j2][0] = *(const bf16x8*)&ldsB[p][o];                       \
      bF[qn][j2][1] = *(const bf16x8*)&ldsB[p][o ^ 32];                  \
    } } while (0)
#define MFMA_Q(qm, qn) do { _Pragma("unroll")                            \
    for (int i2 = 0; i2 < 4; ++i2) { _Pragma("unroll")                   \
      for (int j2 = 0; j2 < 2; ++j2) {                                   \
        floatx4& c = acc[(qm) * 4 + i2][(qn) * 2 + j2];                  \
        c = __builtin_amdgcn_mfma_f32_16x16x32_bf16(aF[i2][0], bF[qn][j2][0], c, 0, 0, 0); \
        c = __builtin_amdgcn_mfma_f32_16x16x32_bf16(aF[i2][1], bF[qn][j2][1], c, 0, 0, 0); \
      } } } while (0)

  // prologue: tile0 complete + tile1 B-halves; wait tile0 (leave tile1.B in flight)
  STG_B(0, 0, 0); STG_B(0, 1, 0);
  STG_A(0, 0, 0); STG_A(0, 1, 0);
  STG_B(1, 0, 1); STG_B(1, 1, 1);
  asm volatile("s_waitcnt vmcnt(4)" ::: "memory");
  BARRIER();

#pragma unroll 2
  for (int t = 0; t < NT; ++t) {
    const int p = t & 1, q = p ^ 1;
    const int t1 = (t + 1) & (NT - 1), t2 = (t + 2) & (NT - 1);

    // ---- phase 1: quadrant (0,0)
    LD_A(p, 0); LD_B(p, 0);
    STG_A(q, 0, t1);
    BARRIER();
    asm volatile("s_waitcnt lgkmcnt(0)" ::: "memory");
    __builtin_amdgcn_sched_barrier(0);
    __builtin_amdgcn_s_setprio(1); MFMA_Q(0, 0); __builtin_amdgcn_s_setprio(0);
    BARRIER();

    // ---- phase 2: quadrant (0,1)
    LD_B(p, 1);
    STG_A(q, 1, t1);
    BARRIER();
    asm volatile("s_waitcnt lgkmcnt(0)" ::: "memory");
    __builtin_amdgcn_sched_barrier(0);
    __builtin_amdgcn_s_setprio(1); MFMA_Q(0, 1); __builtin_amdgcn_s_setprio(0);
    BARRIER();

    // ---- phase 3: quadrant (1,0)
    LD_A(p, 1);
    STG_B(p, 0, t2);
    BARRIER();
    asm volatile("s_waitcnt lgkmcnt(0)" ::: "memory");
    __builtin_amdgcn_sched_barrier(0);
    __builtin_amdgcn_s_setprio(1); MFMA_Q(1, 0); __builtin_amdgcn_s_setprio(0);
    BARRIER();

    // ---- phase 4: quadrant (1,1); counted vmcnt AFTER the MFMA cluster
    STG_B(p, 1, t2);
    BARRIER();
    __builtin_amdgcn_s_setprio(1); MFMA_Q(1, 1); __builtin_amdgcn_s_setprio(0);
    asm volatile("s_waitcnt vmcnt(4)" ::: "memory");
    BARRIER();
  }

  // C/D layout (m89-verified): col(n)=lane&15, row(m)=quad*4+reg
#pragma unroll
  for (int i = 0; i < 8; ++i) {
    const int mbase = m0 + wm * 128 + i * 16 + quad * 4;
#pragma unroll
    for (int j = 0; j < 4; ++j) {
      const int n = n0 + wn * 64 + j * 16 + lrow;
#pragma unroll
      for (int r = 0; r < 4; ++r)
        C[(size_t)(mbase + r) * N + n] = (bf16_t)acc[i][j][r];
    }
  }
#undef STG_A
#undef STG_B
#undef LD_A
#undef LD_B
#undef MFMA_Q
}

// ---------------- fused epilogue: WAVE-PER-ROW, fully vectorized ------------
// 4 waves/block, one batch row per wave. Lane l owns four h-quads:
// h = c*256 + l*4 + k (c=0..3, k=0..3). Gate-interleaved IG/HG (n' = h*4+g)
// makes each h-quad a 16-consecutive-bf16 chunk -> 2x bf16x8 loads. Params,
// cx, wc/bc, and outputs are all lane-contiguous float4 (G13-compliant).
// Both LN reductions are 64-lane __shfl_xor butterflies (no LDS, no barrier).
__device__ inline float sigmoid_f(float x) { return 1.0f / (1.0f + __expf(-x)); }
__device__ inline float tanh_f(float x) {
  float e = __expf(2.0f * x);
  return 1.0f - 2.0f / (e + 1.0f);   // safe at +/-inf
}

__global__ __launch_bounds__(256) void ln_lstm_epi_wave2(
    const bf16_t* __restrict__ IG, const bf16_t* __restrict__ HG,
    const float* __restrict__ cx,
    const float* __restrict__ wi, const float* __restrict__ bi,
    const float* __restrict__ wh, const float* __restrict__ bh,
    const float* __restrict__ wc, const float* __restrict__ bc,
    float* __restrict__ hy_out, float* __restrict__ cy_out) {
  const int l = threadIdx.x & 63;
  const int b = blockIdx.x * 4 + (threadIdx.x >> 6);

  const bf16_t* igp = IG + (size_t)b * 4096;
  const bf16_t* hgp = HG + (size_t)b * 4096;

  bf16x8 igv[4][2], hgv[4][2];
  float4 cx4[4];
#pragma unroll
  for (int c = 0; c < 4; ++c) {
    const int n0 = c * 1024 + l * 16;     // elem offset of this chunk in row
    igv[c][0] = *(const bf16x8*)(igp + n0);
    igv[c][1] = *(const bf16x8*)(igp + n0 + 8);
    hgv[c][0] = *(const bf16x8*)(hgp + n0);
    hgv[c][1] = *(const bf16x8*)(hgp + n0 + 8);
    cx4[c] = *(const float4*)(cx + (size_t)b * 1024 + c * 256 + l * 4);
  }

  // ---- LN stats over the two 4096-wide gate rows
  float si = 0, qi = 0, sh = 0, qh = 0;
#pragma unroll
  for (int c = 0; c < 4; ++c)
#pragma unroll
    for (int hf = 0; hf < 2; ++hf)
#pragma unroll
      for (int e = 0; e < 8; ++e) {
        const float a = (float)igv[c][hf][e], d = (float)hgv[c][hf][e];
        si += a; qi = fmaf(a, a, qi);
        sh += d; qh = fmaf(d, d, qh);
      }
#pragma unroll
  for (int off = 1; off < 64; off <<= 1) {
    si += __shfl_xor(si, off); qi += __shfl_xor(qi, off);
    sh += __shfl_xor(sh, off); qh += __shfl_xor(qh, off);
  }
  const float invN = 1.0f / 4096.0f;
  const float mui = si * invN, muh = sh * invN;
  const float rsi = rsqrtf(fmaxf(qi * invN - mui * mui, 0.0f) + 1e-5f);
  const float rsh = rsqrtf(fmaxf(qh * invN - muh * muh, 0.0f) + 1e-5f);

  // ---- gates -> cell, accumulating c-LN stats
  float cv[16], ov[16];
  float sc = 0, qc = 0;
#pragma unroll
  for (int c = 0; c < 4; ++c) {
    const int h0 = c * 256 + l * 4;
    float4 wiv[4], biv[4], whv[4], bhv[4];
#pragma unroll
    for (int g = 0; g < 4; ++g) {
      wiv[g] = *(const float4*)(wi + g * 1024 + h0);
      biv[g] = *(const float4*)(bi + g * 1024 + h0);
      whv[g] = *(const float4*)(wh + g * 1024 + h0);
      bhv[g] = *(const float4*)(bh + g * 1024 + h0);
    }
#pragma unroll
    for (int k = 0; k < 4; ++k) {
      float G[4];
#pragma unroll
      for (int g = 0; g < 4; ++g) {
        const int idx = k * 4 + g;          // elem within 16-wide chunk
        const float gi = (float)igv[c][idx >> 3][idx & 7];
        const float gh = (float)hgv[c][idx >> 3][idx & 7];
        G[g] = (gi - mui) * rsi * ((const float*)&wiv[g])[k] + ((const float*)&biv[g])[k] +
               (gh - muh) * rsh * ((const float*)&whv[g])[k] + ((const float*)&bhv[g])[k];
      }
      const float in_g = sigmoid_f(G[0]);
      const float fo_g = sigmoid_f(G[1]);
      const float ce_g = tanh_f(G[2]);
      ov[c * 4 + k] = sigmoid_f(G[3]);
      const float cc = fo_g * ((const float*)&cx4[c])[k] + in_g * ce_g;
      cv[c * 4 + k] = cc;
      sc += cc; qc = fmaf(cc, cc, qc);
    }
  }
#pragma unroll
  for (int off = 1; off < 64; off <<= 1) {
    sc += __shfl_xor(sc, off); qc += __shfl_xor(qc, off);
  }
  const float invH = 1.0f / 1024.0f;
  const float muc = sc * invH;
  const float rsc = rsqrtf(fmaxf(qc * invH - muc * muc, 0.0f) + 1e-5f);

  // ---- c-LN + output, float4 stores
#pragma unroll
  for (int c = 0; c < 4; ++c) {
    const int h0 = c * 256 + l * 4;
    const float4 wc4 = *(const float4*)(wc + h0);
    const float4 bc4 = *(const float4*)(bc + h0);
    float4 cyv, hyv;
#pragma unroll
    for (int k = 0; k < 4; ++k) {
      const float cyn = (cv[c * 4 + k] - muc) * rsc * ((const float*)&wc4)[k] +
                        ((const float*)&bc4)[k];
      ((float*)&cyv)[k] = cyn;
      ((float*)&hyv)[k] = ov[c * 4 + k] * tanh_f(cyn);
    }
    *(float4*)(cy_out + (size_t)b * 1024 + h0) = cyv;
    *(float4*)(hy_out + (size_t)b * 1024 + h0) = hyv;
  }
}

extern "C" void kernel_launch(void* const* d_in, const int* in_sizes, int n_in,
                              void* d_out, int out_size, void* d_ws, size_t ws_size,
                              hipStream_t stream) {
  const float* input  = (const float*)d_in[0];
  const float* hx     = (const float*)d_in[1];
  const float* cx     = (const float*)d_in[2];
  const float* w_ih   = (const float*)d_in[3];
  const float* w_hh   = (const float*)d_in[4];
  const float* ln_i_w = (const float*)d_in[5];
  const float* ln_i_b = (const float*)d_in[6];
  const float* ln_h_w = (const float*)d_in[7];
  const float* ln_h_b = (const float*)d_in[8];
  const float* ln_c_w = (const float*)d_in[9];
  const float* ln_c_b = (const float*)d_in[10];

  float* out = (float*)d_out;
  float* hy = out;
  float* cy = out + (size_t)B_ * H_;

  // workspace (bf16): A 16MB | H 16MB | Wih 8MB | Whh 8MB | IG 64MB | HG 64MB
  bf16_t* Abf = (bf16_t*)d_ws;
  bf16_t* Hbf = Abf + (size_t)B_ * K_;
  bf16_t* Wib = Hbf + (size_t)B_ * K_;
  bf16_t* Whb = Wib + (size_t)G4 * K_;
  bf16_t* IG  = Whb + (size_t)G4 * K_;
  bf16_t* HG  = IG + (size_t)B_ * G4;

  prep_all<<<24576, 256, 0, stream>>>(input, hx, w_ih, w_hh, Abf, Hbf, Wib, Whb);

  gemm_bt_dual8<<<dim3(G4 / 256, B_ / 256, 2), 512, 0, stream>>>(Abf, Hbf, Wib, Whb, IG, HG);

  ln_lstm_epi_wave2<<<B_ / 4, 256, 0, stream>>>(IG, HG, cx, ln_i_w, ln_i_b,
                                                ln_h_w, ln_h_b, ln_c_w, ln_c_b, hy, cy);
}